// Round 1
// baseline (1052.988 us; speedup 1.0000x reference)
//
#include <hip/hip_runtime.h>
#include <cstddef>

#define H_ 128   // hidden/channels/state
#define F_ 128   // freq bins
#define B_ 4     // batch
#define T_ 512   // time
#define TC 32    // time chunk
#define NCHUNK (T_ / TC)

// One block per (param-bin i, j). Faithful-to-torch scramble:
//   k = i*4 + j ; source batch b' = k >> 7 ; source freq f' = k & 127
//   params indexed by i ; output goes to out[j, h, i, t]
__global__ __launch_bounds__(256, 2)
void lru_fused_kernel(const float* __restrict__ x,
                      const float* __restrict__ nu_log,
                      const float* __restrict__ theta_log,
                      const float* __restrict__ gamma_log,
                      const float* __restrict__ Bre,
                      const float* __restrict__ Bim,
                      const float* __restrict__ Cre,
                      const float* __restrict__ Cim,
                      const float* __restrict__ Dw,
                      float* __restrict__ out)
{
    // xs (phase 1/2) aliases hs_re/hs_im (phase 3/4): xs dead after phase 2.
    __shared__ float smem[2 * 128 * 33];
    __shared__ float us_re[TC][H_ + 4];
    __shared__ float us_im[TC][H_ + 4];

    float (*xs)[33]    = (float(*)[33])smem;            // [c][t]
    float (*hs_re)[33] = (float(*)[33])smem;            // [n][t]
    float (*hs_im)[33] = (float(*)[33])(smem + 128 * 33);

    const int bid  = blockIdx.x;        // = i*4 + j
    const int ibin = bid >> 2;          // param bin i
    const int jj   = bid & 3;           // output "batch" axis
    const int bp   = bid >> 7;          // source batch
    const int fp   = bid & 127;         // source freq
    const int tid  = threadIdx.x;
    const int n    = tid & 127;         // state index n (doubles as output h)
    const int th   = tid >> 7;          // t-half: 0 -> t 0..15, 1 -> t 16..31

    // per-thread LRU params for (ibin, n)
    const float lam_mod = expf(-expf(nu_log[ibin * H_ + n]));
    const float theta   = expf(theta_log[ibin * H_ + n]);
    const float lam_re  = lam_mod * cosf(theta);
    const float lam_im  = lam_mod * sinf(theta);
    const float gam     = expf(gamma_log[ibin * H_ + n]);
    const float Dh      = Dw[ibin * H_ + n];

    const float* Brow_re = Bre + ((size_t)ibin * H_ + n) * H_;
    const float* Brow_im = Bim + ((size_t)ibin * H_ + n) * H_;
    const float* Crow_re = Cre + ((size_t)ibin * H_ + n) * H_;
    const float* Crow_im = Cim + ((size_t)ibin * H_ + n) * H_;

    const float* xbase = x + ((size_t)bp * H_) * (F_ * T_) + (size_t)fp * T_;
    const float* xg    = x + (((size_t)bp * H_ + n) * F_ + fp) * T_;   // row for D*x term
    float*       og    = out + (((size_t)jj * H_ + n) * F_ + ibin) * T_;

    float hr = 0.f, hi = 0.f;   // scan state (threads 0..127)

    for (int ch = 0; ch < NCHUNK; ++ch) {
        const int t0 = ch * TC;

        // ---- phase 1: stage x chunk -> xs[c][t] ----
        #pragma unroll
        for (int ii = 0; ii < 16; ++ii) {
            int e = ii * 256 + tid;       // 0..4095
            int c = e >> 5;
            int t = e & 31;
            xs[c][t] = xbase[(size_t)c * (F_ * T_) + t0 + t];
        }
        __syncthreads();

        // ---- phase 2: u[t][n] = gamma[n] * sum_c xs[c][t] * B[n][c] ----
        {
            float ar[16], ai[16];
            #pragma unroll
            for (int q = 0; q < 16; ++q) { ar[q] = 0.f; ai[q] = 0.f; }

            #pragma unroll 4
            for (int c4 = 0; c4 < H_ / 4; ++c4) {
                float4 br = ((const float4*)Brow_re)[c4];
                float4 bi = ((const float4*)Brow_im)[c4];
                #pragma unroll
                for (int u = 0; u < 4; ++u) {
                    float brv = reinterpret_cast<const float*>(&br)[u];
                    float biv = reinterpret_cast<const float*>(&bi)[u];
                    const float* xr = &xs[c4 * 4 + u][th * 16];
                    #pragma unroll
                    for (int q = 0; q < 16; ++q) {
                        float xv = xr[q];
                        ar[q] = fmaf(brv, xv, ar[q]);
                        ai[q] = fmaf(biv, xv, ai[q]);
                    }
                }
            }
            #pragma unroll
            for (int q = 0; q < 16; ++q) {
                us_re[th * 16 + q][n] = gam * ar[q];
                us_im[th * 16 + q][n] = gam * ai[q];
            }
        }
        __syncthreads();

        // ---- phase 3: sequential scan, h = lam*h + u ; store transposed ----
        if (tid < 128) {
            #pragma unroll
            for (int t = 0; t < TC; ++t) {
                float ur = us_re[t][n];
                float ui = us_im[t][n];
                float nr = fmaf(lam_re, hr, fmaf(-lam_im, hi, ur));
                float ni = fmaf(lam_re, hi, fmaf(lam_im, hr, ui));
                hr = nr; hi = ni;
                hs_re[n][t] = hr;
                hs_im[n][t] = hi;
            }
        }
        __syncthreads();

        // ---- phase 4: y[t][h] = sum_n h[t][n]·C[h][n] (re) + D[h]*x ----
        {
            float acc[16];
            #pragma unroll
            for (int q = 0; q < 16; ++q) acc[q] = 0.f;

            #pragma unroll 4
            for (int m4 = 0; m4 < H_ / 4; ++m4) {
                float4 cr = ((const float4*)Crow_re)[m4];
                float4 ci = ((const float4*)Crow_im)[m4];
                #pragma unroll
                for (int u = 0; u < 4; ++u) {
                    float crv = reinterpret_cast<const float*>(&cr)[u];
                    float civ = reinterpret_cast<const float*>(&ci)[u];
                    int m = m4 * 4 + u;
                    const float* hr_ = &hs_re[m][th * 16];
                    const float* hi_ = &hs_im[m][th * 16];
                    #pragma unroll
                    for (int q = 0; q < 16; ++q) {
                        acc[q] = fmaf(crv,  hr_[q], acc[q]);
                        acc[q] = fmaf(-civ, hi_[q], acc[q]);
                    }
                }
            }

            const float* xrow = xg + t0 + th * 16;
            float*       orow = og + t0 + th * 16;
            #pragma unroll
            for (int q = 0; q < 16; ++q) {
                orow[q] = fmaf(Dh, xrow[q], acc[q]);
            }
        }
        __syncthreads();   // protects xs/hs alias + us before next chunk
    }
}

extern "C" void kernel_launch(void* const* d_in, const int* in_sizes, int n_in,
                              void* d_out, int out_size, void* d_ws, size_t ws_size,
                              hipStream_t stream) {
    (void)in_sizes; (void)n_in; (void)d_ws; (void)ws_size; (void)out_size;
    const float* x         = (const float*)d_in[0];
    const float* nu_log    = (const float*)d_in[1];
    const float* theta_log = (const float*)d_in[2];
    const float* gamma_log = (const float*)d_in[3];
    const float* Bre       = (const float*)d_in[4];
    const float* Bim       = (const float*)d_in[5];
    const float* Cre       = (const float*)d_in[6];
    const float* Cim       = (const float*)d_in[7];
    const float* Dw        = (const float*)d_in[8];
    float* out = (float*)d_out;

    dim3 grid(F_ * B_);   // 512 blocks: one per (i, j)
    dim3 block(256);
    hipLaunchKernelGGL(lru_fused_kernel, grid, block, 0, stream,
                       x, nu_log, theta_log, gamma_log,
                       Bre, Bim, Cre, Cim, Dw, out);
}

// Round 2
// 118.663 us; speedup vs baseline: 8.8738x; 8.8738x over previous
//
#include <hip/hip_runtime.h>
#include <hip/hip_bf16.h>
#include <cstddef>

#define H_ 128   // hidden/channels/state
#define F_ 128   // freq bins
#define B_ 4     // batch
#define T_ 512   // time
#define TC 64    // time chunk
#define NCH (T_ / TC)

typedef short short8 __attribute__((ext_vector_type(8)));   // 8 bf16 (4 VGPRs)
typedef float f32x4 __attribute__((ext_vector_type(4)));
typedef float f4 __attribute__((ext_vector_type(4)));
typedef unsigned int uint32;

static __device__ __forceinline__ unsigned short f2bf(float x) {
    __hip_bfloat16 h = __float2bfloat16(x);   // RNE
    return __builtin_bit_cast(unsigned short, h);
}

// One block per (param-bin i, j).  k = i*4+j ; b' = k>>7 ; f' = k&127 (verified R1).
__global__ __launch_bounds__(256, 2)
void lru_mfma_kernel(const float* __restrict__ x,
                     const float* __restrict__ nu_log,
                     const float* __restrict__ theta_log,
                     const float* __restrict__ gamma_log,
                     const float* __restrict__ Bre,
                     const float* __restrict__ Bim,
                     const float* __restrict__ Cre,
                     const float* __restrict__ Cim,
                     const float* __restrict__ Dw,
                     float* __restrict__ out)
{
    // x-tile [t][c] bf16, row stride 136 shorts = 272B (16B-aligned, banks spread)
    __shared__ short  xs[TC * 136];
    // u/h interleaved [t][n](re,im) bf16 pairs, row stride 132 uints = 528B
    __shared__ uint32 uh[TC * 132];

    const int bid  = blockIdx.x;
    const int ibin = bid >> 2, jj = bid & 3;
    const int bp   = bid >> 7, fp = bid & 127;
    const int tid  = threadIdx.x;
    const int w    = tid >> 6;          // wave 0..3
    const int lane = tid & 63;
    const int g    = lane >> 4;         // k-group 0..3
    const int c15  = lane & 15;

    // ---- scan params: thread ns = tid&127 owns state chain n=ns ----
    const int ns = tid & 127;
    float lam_re, lam_im;
    {
        float lm = expf(-expf(nu_log[ibin * H_ + ns]));
        float th = expf(theta_log[ibin * H_ + ns]);
        lam_re = lm * cosf(th);
        lam_im = lm * sinf(th);
    }

    // ---- persistent weight fragments (wave w owns n/h tiles {2w, 2w+1}) ----
    short8 bfr[2][4], bfi[2][4];   // B-op for matmul1: [ntile][kblock]
    short8 cf[2][8];               // B-op for matmul2 (K'=256 interleave): [htile][kblock]
    float  gam[2], Dh[2];
    #pragma unroll
    for (int s = 0; s < 2; ++s) {
        const int ncol = (2 * w + s) * 16 + c15;          // n (m1) == h (m2) column
        gam[s] = expf(gamma_log[ibin * H_ + ncol]);
        Dh[s]  = Dw[ibin * H_ + ncol];
        const float* br = Bre + ((size_t)ibin * H_ + ncol) * H_;
        const float* bi = Bim + ((size_t)ibin * H_ + ncol) * H_;
        #pragma unroll
        for (int kb = 0; kb < 4; ++kb) {
            const int c0 = kb * 32 + g * 8;               // 8 consecutive c
            f4 r0 = *(const f4*)(br + c0), r1 = *(const f4*)(br + c0 + 4);
            f4 i0 = *(const f4*)(bi + c0), i1 = *(const f4*)(bi + c0 + 4);
            short8 fr, fi;
            fr[0]=(short)f2bf(r0[0]); fr[1]=(short)f2bf(r0[1]); fr[2]=(short)f2bf(r0[2]); fr[3]=(short)f2bf(r0[3]);
            fr[4]=(short)f2bf(r1[0]); fr[5]=(short)f2bf(r1[1]); fr[6]=(short)f2bf(r1[2]); fr[7]=(short)f2bf(r1[3]);
            fi[0]=(short)f2bf(i0[0]); fi[1]=(short)f2bf(i0[1]); fi[2]=(short)f2bf(i0[2]); fi[3]=(short)f2bf(i0[3]);
            fi[4]=(short)f2bf(i1[0]); fi[5]=(short)f2bf(i1[1]); fi[6]=(short)f2bf(i1[2]); fi[7]=(short)f2bf(i1[3]);
            bfr[s][kb] = fr; bfi[s][kb] = fi;
        }
        const float* cr = Cre + ((size_t)ibin * H_ + ncol) * H_;
        const float* ci = Cim + ((size_t)ibin * H_ + ncol) * H_;
        #pragma unroll
        for (int kb = 0; kb < 8; ++kb) {
            const int n0 = kb * 16 + g * 4;               // 4 consecutive n -> 8 interleaved k'
            f4 vr = *(const f4*)(cr + n0);
            f4 vi = *(const f4*)(ci + n0);
            short8 fc;
            fc[0]=(short)f2bf(vr[0]); fc[1]=(short)f2bf(-vi[0]);
            fc[2]=(short)f2bf(vr[1]); fc[3]=(short)f2bf(-vi[1]);
            fc[4]=(short)f2bf(vr[2]); fc[5]=(short)f2bf(-vi[2]);
            fc[6]=(short)f2bf(vr[3]); fc[7]=(short)f2bf(-vi[3]);
            cf[s][kb] = fc;
        }
    }

    float hr = 0.f, hi = 0.f;          // fp32 scan state, persists across chunks

    const int cstage = tid & 127;       // staging: channel row
    const int thalf  = tid >> 7;        // staging: t half
    const float* xrow = x + (((size_t)bp * H_ + cstage) * F_ + fp) * T_;

    for (int ch = 0; ch < NCH; ++ch) {
        const int t0 = ch * TC;

        // ---- phase A: stage+transpose x chunk -> xs[t][c] bf16 ----
        #pragma unroll
        for (int k = 0; k < 8; ++k) {
            const int tl = thalf * 32 + k * 4;
            f4 v = *(const f4*)(xrow + t0 + tl);
            xs[(tl + 0) * 136 + cstage] = (short)f2bf(v[0]);
            xs[(tl + 1) * 136 + cstage] = (short)f2bf(v[1]);
            xs[(tl + 2) * 136 + cstage] = (short)f2bf(v[2]);
            xs[(tl + 3) * 136 + cstage] = (short)f2bf(v[3]);
        }
        __syncthreads();

        // ---- phase B: U = X^T * B  (two bf16 GEMMs sharing A) ----
        {
            f32x4 ar[4][2], ai[4][2];
            #pragma unroll
            for (int tt = 0; tt < 4; ++tt)
                #pragma unroll
                for (int s = 0; s < 2; ++s) { ar[tt][s] = (f32x4)0.f; ai[tt][s] = (f32x4)0.f; }

            #pragma unroll
            for (int kb = 0; kb < 4; ++kb) {
                #pragma unroll
                for (int tt = 0; tt < 4; ++tt) {
                    short8 a = *(const short8*)(xs + (tt * 16 + c15) * 136 + kb * 32 + g * 8);
                    #pragma unroll
                    for (int s = 0; s < 2; ++s) {
                        ar[tt][s] = __builtin_amdgcn_mfma_f32_16x16x32_bf16(a, bfr[s][kb], ar[tt][s], 0, 0, 0);
                        ai[tt][s] = __builtin_amdgcn_mfma_f32_16x16x32_bf16(a, bfi[s][kb], ai[tt][s], 0, 0, 0);
                    }
                }
            }
            // write u = gamma*acc, interleaved bf16 pairs
            #pragma unroll
            for (int tt = 0; tt < 4; ++tt)
                #pragma unroll
                for (int s = 0; s < 2; ++s) {
                    const int n = (2 * w + s) * 16 + c15;
                    #pragma unroll
                    for (int r = 0; r < 4; ++r) {
                        const int t = tt * 16 + g * 4 + r;
                        float ur = gam[s] * ar[tt][s][r];
                        float ui = gam[s] * ai[tt][s][r];
                        uh[t * 132 + n] = (uint32)f2bf(ur) | ((uint32)f2bf(ui) << 16);
                    }
                }
        }
        __syncthreads();

        // ---- phase C: sequential scan h = lam*h + u (in place, bf16 pairs) ----
        if (tid < 128) {
            uint32* col = uh + ns;
            #pragma unroll
            for (int t = 0; t < TC; ++t) {
                uint32 v = col[t * 132];
                float ur = __uint_as_float(v << 16);
                float ui = __uint_as_float(v & 0xffff0000u);
                float nr = fmaf(lam_re, hr, fmaf(-lam_im, hi, ur));
                float ni = fmaf(lam_re, hi, fmaf(lam_im, hr, ui));
                hr = nr; hi = ni;
                col[t * 132] = (uint32)f2bf(hr) | ((uint32)f2bf(hi) << 16);
            }
        }
        __syncthreads();

        // ---- phase D: Y = hI * CI (K'=256 interleaved) + D*x, store float4 ----
        {
            f32x4 ay[4][2];
            #pragma unroll
            for (int tt = 0; tt < 4; ++tt)
                #pragma unroll
                for (int s = 0; s < 2; ++s) ay[tt][s] = (f32x4)0.f;

            const short* uhs = (const short*)uh;    // row stride 264 shorts
            #pragma unroll
            for (int kb = 0; kb < 8; ++kb) {
                #pragma unroll
                for (int tt = 0; tt < 4; ++tt) {
                    short8 ah = *(const short8*)(uhs + (tt * 16 + c15) * 264 + kb * 32 + g * 8);
                    #pragma unroll
                    for (int s = 0; s < 2; ++s)
                        ay[tt][s] = __builtin_amdgcn_mfma_f32_16x16x32_bf16(ah, cf[s][kb], ay[tt][s], 0, 0, 0);
                }
            }
            #pragma unroll
            for (int tt = 0; tt < 4; ++tt)
                #pragma unroll
                for (int s = 0; s < 2; ++s) {
                    const int h = (2 * w + s) * 16 + c15;
                    const int t = t0 + tt * 16 + g * 4;
                    f4 xv = *(const f4*)(x + (((size_t)bp * H_ + h) * F_ + fp) * T_ + t);
                    f4 y;
                    #pragma unroll
                    for (int r = 0; r < 4; ++r) y[r] = fmaf(Dh[s], xv[r], ay[tt][s][r]);
                    *(f4*)(out + (((size_t)jj * H_ + h) * F_ + ibin) * T_ + t) = y;
                }
        }
        __syncthreads();   // uh/xs reused next chunk
    }
}

extern "C" void kernel_launch(void* const* d_in, const int* in_sizes, int n_in,
                              void* d_out, int out_size, void* d_ws, size_t ws_size,
                              hipStream_t stream) {
    (void)in_sizes; (void)n_in; (void)d_ws; (void)ws_size; (void)out_size;
    const float* x         = (const float*)d_in[0];
    const float* nu_log    = (const float*)d_in[1];
    const float* theta_log = (const float*)d_in[2];
    const float* gamma_log = (const float*)d_in[3];
    const float* Bre       = (const float*)d_in[4];
    const float* Bim       = (const float*)d_in[5];
    const float* Cre       = (const float*)d_in[6];
    const float* Cim       = (const float*)d_in[7];
    const float* Dw        = (const float*)d_in[8];
    float* out = (float*)d_out;

    dim3 grid(F_ * B_);   // 512 blocks: one per (i, j)
    dim3 block(256);
    hipLaunchKernelGGL(lru_mfma_kernel, grid, block, 0, stream,
                       x, nu_log, theta_log, gamma_log,
                       Bre, Bim, Cre, Cim, Dw, out);
}